// Round 14
// baseline (438.178 us; speedup 1.0000x reference)
//
#include <hip/hip_runtime.h>
#include <hip/hip_fp16.h>
#include <math.h>

static constexpr int D = 128;
static constexpr int CAP = 64;            // bucket capacity; max degree ~45 for E/N=16 Poisson
static constexpr float EPS_BN = 1e-3f;

typedef short short8 __attribute__((ext_vector_type(8)));
typedef short short4v __attribute__((ext_vector_type(4)));
typedef float float4v __attribute__((ext_vector_type(4)));

__device__ __forceinline__ float gelu_exact(float x) {
    return 0.5f * x * (1.0f + erff(x * 0.70710678118654752f));
}

__device__ __forceinline__ void f32_to_hilo(float f, short& h, short& l) {
    unsigned u = __float_as_uint(f);
    h = (short)(u >> 16);
    float hf = __uint_as_float(u & 0xFFFF0000u);
    unsigned lu = __float_as_uint(f - hf);
    l = (short)(lu >> 16);
}

__device__ __forceinline__ short f32_to_bf16_rne(float f) {
    unsigned u = __float_as_uint(f);
    u += 0x7FFFu + ((u >> 16) & 1u);
    return (short)(u >> 16);
}

__device__ __forceinline__ void cvt_hilo8(const float4& x, const float4& y, short8& h8, short8& l8) {
    short h, l;
    f32_to_hilo(x.x, h, l); h8[0] = h; l8[0] = l;
    f32_to_hilo(x.y, h, l); h8[1] = h; l8[1] = l;
    f32_to_hilo(x.z, h, l); h8[2] = h; l8[2] = l;
    f32_to_hilo(x.w, h, l); h8[3] = h; l8[3] = l;
    f32_to_hilo(y.x, h, l); h8[4] = h; l8[4] = l;
    f32_to_hilo(y.y, h, l); h8[5] = h; l8[5] = l;
    f32_to_hilo(y.z, h, l); h8[6] = h; l8[6] = l;
    f32_to_hilo(y.w, h, l); h8[7] = h; l8[7] = l;
}

__device__ __forceinline__ short8 cvt_rne8(const float4& x, const float4& y) {
    short8 r;
    r[0] = f32_to_bf16_rne(x.x); r[1] = f32_to_bf16_rne(x.y);
    r[2] = f32_to_bf16_rne(x.z); r[3] = f32_to_bf16_rne(x.w);
    r[4] = f32_to_bf16_rne(y.x); r[5] = f32_to_bf16_rne(y.y);
    r[6] = f32_to_bf16_rne(y.z); r[7] = f32_to_bf16_rne(y.w);
    return r;
}

// ---------------- fold args ----------------
struct FoldArgs {
    const float* g[6]; const float* be[6]; const float* mu[6];
    const float* var[6]; const float* w[6]; const float* bi[6];
    short* wh[6]; short* wl[6]; float* bp[6]; int K[6];
};

// ---------------- BN fold (standalone): 6 FFNs' weights -> bf16 hi/lo + folded bias
__global__ void k_fold(FoldArgs fa) {
    __shared__ float sm[4];
    const int tid = threadIdx.x;
    const int lane = tid & 63, wvi = tid >> 6;
    const int f = blockIdx.x >> 7;      // 0..5
    const int c = blockIdx.x & 127;     // 0..127
    const int K = fa.K[f];
    const float* g = fa.g[f]; const float* be = fa.be[f];
    const float* mu = fa.mu[f]; const float* var = fa.var[f];
    const float* w = fa.w[f]; const float* bi = fa.bi[f];
    short* wh = fa.wh[f]; short* wl = fa.wl[f]; float* bp = fa.bp[f];
    float part = 0.f;
    for (int k = tid; k < K; k += blockDim.x) {
        float a = g[k] / sqrtf(var[k] + EPS_BN);
        float wv = w[k * D + c];
        float prod = a * wv;
        short hh, ll;
        f32_to_hilo(prod, hh, ll);
        wh[c * K + k] = hh;
        wl[c * K + k] = ll;
        part += (be[k] - mu[k] * a) * wv;
    }
    for (int off = 32; off > 0; off >>= 1) part += __shfl_down(part, off, 64);
    if (lane == 0) sm[wvi] = part;
    __syncthreads();
    if (tid == 0) bp[c] = bi[c] + sm[0] + sm[1] + sm[2] + sm[3];
}

// ---------------- fused fill + pre-FFN + conv1-prepare ----------------
// Fill is pipe-idle and block-count-insensitive (R9) -> co-residency with MFMA
// work overlaps to ~max. R13: 512/512 split made pre+c1p the pole (~85us vs
// fill ~61). Rebalance: 256 fill blocks (32/group, ~49 edges/thread) + 768 pre
// blocks (1.5x parallelism). First dispatch round: blocks 0-255 fill + 256-511
// pre -> 1 of each per CU; remaining 512 pre blocks backfill.
__global__ void __launch_bounds__(512) k_fillpre(
    const int* __restrict__ edges, const float* __restrict__ ew,
    int* __restrict__ cnt, float* __restrict__ sums, unsigned* __restrict__ cw,
    int E, int N,
    const float* __restrict__ A0, const short* __restrict__ Wh,
    const short* __restrict__ Wl, const float* __restrict__ bp,
    float* __restrict__ outf,
    const short* __restrict__ Wh1, const float* __restrict__ bp1,
    __half* __restrict__ yh)
{
    constexpr int K = 128;
    constexpr int WSZ = 128 * K;              // shorts per hi/lo buffer
    __shared__ short Wlds[2 * WSZ];           // 64 KB
    __shared__ short xbuf[2][16][136];        // strip rows as bf16 (pad 136)
    __shared__ float sm[8];

    const int tid = threadIdx.x;
    const int lane = tid & 63;
    const int wvi = tid >> 6;

    if ((int)blockIdx.x < 256) {
        // ---------------- fill role (256 blocks x 512 thr, 8-group partition) ----
        const int rid = blockIdx.x;
        const int g = rid & 7;
        const int bid = rid >> 3;             // 0..31
        const int gstride = 32 * 512;
        const int N8 = (N + 7) >> 3;
        const int lo = g * N8;
        const int hi = min(lo + N8, N);
        float s = 0.f;
        for (int e = bid * 512 + tid; e < E; e += gstride) {
            int dst = edges[e];
            if (dst >= lo && dst < hi) {
                int src = edges[E + e];
                float w = ew[e];
                s += w;
                unsigned short wb = __half_as_ushort(__float2half(w));
                int idx = atomicAdd(&cnt[dst], 1);
                if (idx < CAP)
                    cw[(size_t)dst * CAP + idx] = ((unsigned)src << 16) | (unsigned)wb;
            }
        }
        for (int off = 32; off > 0; off >>= 1) s += __shfl_down(s, off, 64);
        if (lane == 0) sm[wvi] = s;
        __syncthreads();
        if (tid == 0) {
            float t = 0.f;
            #pragma unroll
            for (int i = 0; i < 8; i++) t += sm[i];
            if (t != 0.f) atomicAdd(sums, t);
        }
        return;
    }

    // ---------------- pre-FFN + c1p role (768 blocks) ----------------
    const int fbid = blockIdx.x - 256;        // 0..767
    constexpr int NBLK = 768;

    // stage pre W once: LDS[c*K + k] = W[c*K + (k ^ ((c&7)<<3))]
    #pragma unroll
    for (int it = 0; it < (2 * WSZ) / (512 * 8); ++it) {
        int s = it * 4096 + tid * 8;
        int buf = s / WSZ;
        int rem = s - buf * WSZ;
        int c = rem / K;
        int kk = (rem & (K - 1)) ^ ((c & 7) << 3);
        const short* src = (buf ? Wl : Wh) + c * K + kk;
        *(short8*)&Wlds[s] = *(const short8*)src;
    }
    __syncthreads();

    const int wv = tid >> 6;
    const int ssub = wv >> 2;
    const int wc = wv & 3;
    const int m = lane & 15;
    const int quad = lane >> 4;
    const int nstrips = (N + 15) >> 4;
    constexpr int STRIDE = NBLK * 2;

    // grid-uniform trip count (barriers inside the loop)
    int remw = nstrips - fbid * 2;
    int nit = remw > 0 ? (remw + STRIDE - 1) / STRIDE : 0;

    for (int it = 0; it < nit; ++it) {
        const int strip = fbid * 2 + ssub + it * STRIDE;
        const bool active = strip < nstrips;
        float4v acc[2];
        acc[0] = (float4v){0.f, 0.f, 0.f, 0.f};
        acc[1] = (float4v){0.f, 0.f, 0.f, 0.f};

        if (active) {
            int r = strip * 16 + m;
            if (r >= N) r = N - 1;
            const float* pA0 = A0 + (size_t)r * D;

            float4 a[2][4];
            {
                const float4* s4 = (const float4*)pA0 + quad * 2;
                a[0][0] = s4[0]; a[0][1] = s4[1]; a[0][2] = s4[8]; a[0][3] = s4[9];
            }
            {
                const float4* s4 = (const float4*)(pA0 + 64) + quad * 2;
                a[1][0] = s4[0]; a[1][1] = s4[1]; a[1][2] = s4[8]; a[1][3] = s4[9];
            }

            #pragma unroll
            for (int cc = 0; cc < 2; ++cc) {
                #pragma unroll
                for (int ks = 0; ks < 2; ++ks) {
                    const int kk = cc * 64 + ks * 32 + quad * 8;
                    short8 ah, al;
                    cvt_hilo8(a[cc][ks * 2], a[cc][ks * 2 + 1], ah, al);
                    #pragma unroll
                    for (int tj = 0; tj < 2; ++tj) {
                        const int c = wc * 32 + tj * 16 + m;
                        const int idx = c * K + (kk ^ ((c & 7) << 3));
                        short8 bh = *(const short8*)&Wlds[idx];
                        short8 bl = *(const short8*)&Wlds[WSZ + idx];
                        acc[tj] = __builtin_amdgcn_mfma_f32_16x16x32_bf16(al, bh, acc[tj], 0, 0, 0);
                        acc[tj] = __builtin_amdgcn_mfma_f32_16x16x32_bf16(ah, bl, acc[tj], 0, 0, 0);
                        acc[tj] = __builtin_amdgcn_mfma_f32_16x16x32_bf16(ah, bh, acc[tj], 0, 0, 0);
                    }
                }
            }

            // epilogue: bias + gelu; write xA (f32 global) + xbuf (bf16 LDS)
            #pragma unroll
            for (int tj = 0; tj < 2; ++tj) {
                float bv = bp[wc * 32 + tj * 16 + m];
                #pragma unroll
                for (int r4 = 0; r4 < 4; ++r4)
                    acc[tj][r4] = gelu_exact(acc[tj][r4] + bv);
            }
            #pragma unroll
            for (int r4 = 0; r4 < 4; ++r4) {
                int rib = quad * 4 + r4;
                int row = strip * 16 + rib;
                #pragma unroll
                for (int tj = 0; tj < 2; ++tj) {
                    int col = wc * 32 + tj * 16 + m;
                    if (row < N) outf[(size_t)row * D + col] = acc[tj][r4];
                    xbuf[ssub][rib][col] = f32_to_bf16_rne(acc[tj][r4]);
                }
            }
        }
        __syncthreads();

        if (active) {
            // ---- c1p: yh = gelu(xbuf @ W1 + b1), W1 from global (L2-hot) ----
            float4v acc2[2];
            acc2[0] = (float4v){0.f, 0.f, 0.f, 0.f};
            acc2[1] = (float4v){0.f, 0.f, 0.f, 0.f};
            #pragma unroll
            for (int cc = 0; cc < 2; ++cc) {
                #pragma unroll
                for (int ks = 0; ks < 2; ++ks) {
                    const int kk = cc * 64 + ks * 32 + quad * 8;
                    short8 ah = *(const short8*)&xbuf[ssub][m][kk];
                    #pragma unroll
                    for (int tj = 0; tj < 2; ++tj) {
                        const int c = wc * 32 + tj * 16 + m;
                        short8 bh = *(const short8*)(Wh1 + (size_t)c * 128 + kk);
                        acc2[tj] = __builtin_amdgcn_mfma_f32_16x16x32_bf16(ah, bh, acc2[tj], 0, 0, 0);
                    }
                }
            }
            #pragma unroll
            for (int tj = 0; tj < 2; ++tj) {
                float bv = bp1[wc * 32 + tj * 16 + m];
                #pragma unroll
                for (int r4 = 0; r4 < 4; ++r4)
                    acc2[tj][r4] = gelu_exact(acc2[tj][r4] + bv);
            }
            #pragma unroll
            for (int r4 = 0; r4 < 4; ++r4) {
                int row = strip * 16 + quad * 4 + r4;
                if (row < N) {
                    #pragma unroll
                    for (int tj = 0; tj < 2; ++tj) {
                        int col = wc * 32 + tj * 16 + m;
                        yh[(size_t)row * D + col] = __float2half(acc2[tj][r4]);
                    }
                }
            }
        }
        __syncthreads();                      // xbuf reused next iteration
    }
}

// ---------------- bucket gather-reduce (fp16 payload): red[n] = sum_e w[e]*y[col[e]]
__device__ __forceinline__ void accum8(float* acc, const float4& raw, float w) {
    const __half2* hp = (const __half2*)&raw;
    #pragma unroll
    for (int t = 0; t < 4; t++) {
        float2 f = __half22float2(hp[t]);
        acc[t * 2]     += w * f.x;
        acc[t * 2 + 1] += w * f.y;
    }
}

__global__ void k_reduce(const int* __restrict__ cnt, const unsigned* __restrict__ cw,
                         const float* __restrict__ sums, const __half* __restrict__ y,
                         float* __restrict__ red, int N) {
    int n = blockIdx.x * (blockDim.x >> 6) + (threadIdx.x >> 6);
    if (n >= N) return;
    float inv = 1.0f / sums[0];
    int lane = threadIdx.x & 63;
    int sub = lane >> 4;      // edge slot 0..3
    int q = lane & 15;        // 8-half chunk
    int count = min(cnt[n], CAP);
    int start = n * CAP;
    int end = start + count;
    float acc[8] = {0.f, 0.f, 0.f, 0.f, 0.f, 0.f, 0.f, 0.f};
    int i = start + sub;
    for (; i + 12 < end; i += 16) {
        unsigned c0 = cw[i];
        unsigned c1 = cw[i + 4];
        unsigned c2 = cw[i + 8];
        unsigned c3 = cw[i + 12];
        float4 r0 = *((const float4*)(y + (size_t)(c0 >> 16) * D) + q);
        float4 r1 = *((const float4*)(y + (size_t)(c1 >> 16) * D) + q);
        float4 r2 = *((const float4*)(y + (size_t)(c2 >> 16) * D) + q);
        float4 r3 = *((const float4*)(y + (size_t)(c3 >> 16) * D) + q);
        float w0 = __half2float(__ushort_as_half((unsigned short)(c0 & 0xFFFFu))) * inv;
        float w1 = __half2float(__ushort_as_half((unsigned short)(c1 & 0xFFFFu))) * inv;
        float w2 = __half2float(__ushort_as_half((unsigned short)(c2 & 0xFFFFu))) * inv;
        float w3 = __half2float(__ushort_as_half((unsigned short)(c3 & 0xFFFFu))) * inv;
        accum8(acc, r0, w0);
        accum8(acc, r1, w1);
        accum8(acc, r2, w2);
        accum8(acc, r3, w3);
    }
    for (; i < end; i += 4) {
        unsigned c = cw[i];
        float4 r = *((const float4*)(y + (size_t)(c >> 16) * D) + q);
        float w = __half2float(__ushort_as_half((unsigned short)(c & 0xFFFFu))) * inv;
        accum8(acc, r, w);
    }
    #pragma unroll
    for (int t = 0; t < 8; t++) {
        acc[t] += __shfl_xor(acc[t], 16, 64);
        acc[t] += __shfl_xor(acc[t], 32, 64);
    }
    if (sub == 0) {
        float4 o0 = {acc[0], acc[1], acc[2], acc[3]};
        float4 o1 = {acc[4], acc[5], acc[6], acc[7]};
        *((float4*)(red + (size_t)n * D + q * 8)) = o0;
        *((float4*)(red + (size_t)n * D + q * 8 + 4)) = o1;
    }
}

// ---------------- streaming tall-skinny FFN GEMM, col-split waves ----------------
// BLOCK=1024 for the 128KB-LDS K=256 updates (16 waves/CU; launch_bounds pins
// VGPR cap at 128 — R1 lesson). FUSEP: fuse the NEXT row-local K=128 FFN
// (conv2-prepare) into the L2RES epilogue via bf16 xbuf exchange — same
// pattern as fillpre's c1p fusion; removes a dispatch + a 25.6MB re-read.
template<int K, int BLOCK, bool SPLIT3, bool L2RES, bool OUT16, bool GATHER, bool FUSEP>
__global__ void __launch_bounds__(BLOCK, BLOCK / 256) k_ffn(
    const float* __restrict__ A0, const float* __restrict__ A1,
    const short* __restrict__ Wh, const short* __restrict__ Wl,
    const float* __restrict__ bp, const float* __restrict__ resid,
    float* __restrict__ outf, __half* __restrict__ outh, int N,
    const int* __restrict__ gidx,
    const short* __restrict__ WhP, const float* __restrict__ bpP,
    __half* __restrict__ yhP)
{
    constexpr int NB = SPLIT3 ? 2 : 1;
    constexpr int WSZ = 128 * K;              // shorts per hi/lo buffer
    constexpr int NC = K / 64;                // 64-wide K chunks
    constexpr int SS = BLOCK / 256;           // strip-subs per block
    __shared__ short Wlds[NB * WSZ];          // 32..128 KB
    __shared__ float rsum[SS][16][4];         // per-strip-sub row partial sums (L2RES)
    __shared__ short xbuf[FUSEP ? SS : 1][16][136];  // FUSEP row exchange

    const int tid = threadIdx.x;

    constexpr int ITER = (NB * WSZ) / (BLOCK * 8);
    #pragma unroll
    for (int it = 0; it < ITER; ++it) {
        int s = it * (BLOCK * 8) + tid * 8;
        int buf = s / WSZ;
        int rem = s - buf * WSZ;
        int c = rem / K;
        int kk = (rem & (K - 1)) ^ ((c & 7) << 3);
        const short* src = (buf ? Wl : Wh) + c * K + kk;
        *(short8*)&Wlds[s] = *(const short8*)src;
    }
    __syncthreads();

    const int lane = tid & 63;
    const int wv = tid >> 6;
    const int ssub = wv >> 2;
    const int wc = wv & 3;
    const int m = lane & 15;
    const int quad = lane >> 4;
    const int nstrips = (N + 15) >> 4;
    const int stride = gridDim.x * SS;
    const int base = blockIdx.x * SS + ssub;

    auto body = [&](int strip, bool active) {
        int rr = active ? strip * 16 + m : m;
        if (rr >= N) rr = N - 1;
        const int r = GATHER ? gidx[rr] : rr;
        const float* pA0 = A0 + (size_t)r * D;
        const float* pA1 = (K == 256) ? (A1 + (size_t)r * D) : pA0;

        float4 a[2][4];
        {
            const float4* s4 = (const float4*)pA0 + quad * 2;
            a[0][0] = s4[0]; a[0][1] = s4[1]; a[0][2] = s4[8]; a[0][3] = s4[9];
        }
        {
            const float4* s4 = (const float4*)(pA0 + 64) + quad * 2;
            a[1][0] = s4[0]; a[1][1] = s4[1]; a[1][2] = s4[8]; a[1][3] = s4[9];
        }

        float4v acc[2];
        acc[0] = (float4v){0.f, 0.f, 0.f, 0.f};
        acc[1] = (float4v){0.f, 0.f, 0.f, 0.f};

        #pragma unroll
        for (int cc = 0; cc < NC; ++cc) {
            #pragma unroll
            for (int ks = 0; ks < 2; ++ks) {
                const int kk = cc * 64 + ks * 32 + quad * 8;
                short8 ah, al;
                if (SPLIT3) cvt_hilo8(a[cc & 1][ks * 2], a[cc & 1][ks * 2 + 1], ah, al);
                else        ah = cvt_rne8(a[cc & 1][ks * 2], a[cc & 1][ks * 2 + 1]);
                #pragma unroll
                for (int tj = 0; tj < 2; ++tj) {
                    const int c = wc * 32 + tj * 16 + m;
                    const int idx = c * K + (kk ^ ((c & 7) << 3));
                    short8 bh = *(const short8*)&Wlds[idx];
                    if (SPLIT3) {
                        short8 bl = *(const short8*)&Wlds[WSZ + idx];
                        acc[tj] = __builtin_amdgcn_mfma_f32_16x16x32_bf16(al, bh, acc[tj], 0, 0, 0);
                        acc[tj] = __builtin_amdgcn_mfma_f32_16x16x32_bf16(ah, bl, acc[tj], 0, 0, 0);
                    }
                    acc[tj] = __builtin_amdgcn_mfma_f32_16x16x32_bf16(ah, bh, acc[tj], 0, 0, 0);
                }
            }
            if (cc + 2 < NC) {
                const int n2 = cc + 2;
                const float* src = (K == 256 && n2 >= 2) ? pA1 : pA0;
                const int kb = (K == 256) ? ((n2 & 1) * 64) : (n2 * 64);
                const float4* s4 = (const float4*)(src + kb) + quad * 2;
                a[cc & 1][0] = s4[0]; a[cc & 1][1] = s4[1];
                a[cc & 1][2] = s4[8]; a[cc & 1][3] = s4[9];
            }
        }

        #pragma unroll
        for (int tj = 0; tj < 2; ++tj) {
            float bv = bp[wc * 32 + tj * 16 + m];
            #pragma unroll
            for (int r4 = 0; r4 < 4; ++r4)
                acc[tj][r4] = gelu_exact(acc[tj][r4] + bv);
        }

        if (L2RES) {
            float ss[4];
            #pragma unroll
            for (int r4 = 0; r4 < 4; ++r4) {
                float v = acc[0][r4] * acc[0][r4] + acc[1][r4] * acc[1][r4];
                v += __shfl_xor(v, 1, 64);
                v += __shfl_xor(v, 2, 64);
                v += __shfl_xor(v, 4, 64);
                v += __shfl_xor(v, 8, 64);
                ss[r4] = v;
            }
            if (m == 0) {
                #pragma unroll
                for (int r4 = 0; r4 < 4; ++r4) rsum[ssub][quad * 4 + r4][wc] = ss[r4];
            }
            __syncthreads();
            #pragma unroll
            for (int r4 = 0; r4 < 4; ++r4) {
                const int rib = quad * 4 + r4;
                float tot = rsum[ssub][rib][0] + rsum[ssub][rib][1]
                          + rsum[ssub][rib][2] + rsum[ssub][rib][3];
                float inv = 1.0f / fmaxf(sqrtf(tot), 1e-12f);
                int row = strip * 16 + rib;
                if (active && row < N) {
                    #pragma unroll
                    for (int tj = 0; tj < 2; ++tj) {
                        int col = wc * 32 + tj * 16 + m;
                        float v = acc[tj][r4] * inv + resid[(size_t)row * D + col];
                        outf[(size_t)row * D + col] = v;
                        if (FUSEP) xbuf[ssub][rib][col] = f32_to_bf16_rne(v);
                    }
                }
            }
            if (FUSEP) {
                __syncthreads();              // xbuf ready
                if (active) {
                    // fused conv2-prepare: yhP = gelu(xbuf @ WP + bP)
                    float4v acc2[2];
                    acc2[0] = (float4v){0.f, 0.f, 0.f, 0.f};
                    acc2[1] = (float4v){0.f, 0.f, 0.f, 0.f};
                    #pragma unroll
                    for (int cc = 0; cc < 2; ++cc) {
                        #pragma unroll
                        for (int ks = 0; ks < 2; ++ks) {
                            const int kk = cc * 64 + ks * 32 + quad * 8;
                            short8 ah = *(const short8*)&xbuf[ssub][m][kk];
                            #pragma unroll
                            for (int tj = 0; tj < 2; ++tj) {
                                const int c = wc * 32 + tj * 16 + m;
                                short8 bh = *(const short8*)(WhP + (size_t)c * 128 + kk);
                                acc2[tj] = __builtin_amdgcn_mfma_f32_16x16x32_bf16(ah, bh, acc2[tj], 0, 0, 0);
                            }
                        }
                    }
                    #pragma unroll
                    for (int tj = 0; tj < 2; ++tj) {
                        float bv = bpP[wc * 32 + tj * 16 + m];
                        #pragma unroll
                        for (int r4 = 0; r4 < 4; ++r4)
                            acc2[tj][r4] = gelu_exact(acc2[tj][r4] + bv);
                    }
                    #pragma unroll
                    for (int r4 = 0; r4 < 4; ++r4) {
                        int row = strip * 16 + quad * 4 + r4;
                        if (row < N) {
                            #pragma unroll
                            for (int tj = 0; tj < 2; ++tj) {
                                int col = wc * 32 + tj * 16 + m;
                                yhP[(size_t)row * D + col] = __float2half(acc2[tj][r4]);
                            }
                        }
                    }
                }
            }
            __syncthreads();                  // rsum/xbuf reused next iteration
        } else {
            #pragma unroll
            for (int r4 = 0; r4 < 4; ++r4) {
                int row = strip * 16 + quad * 4 + r4;
                if (active && row < N) {
                    #pragma unroll
                    for (int tj = 0; tj < 2; ++tj) {
                        int col = wc * 32 + tj * 16 + m;
                        if (OUT16) outh[(size_t)row * D + col] = __float2half(acc[tj][r4]);
                        else       outf[(size_t)row * D + col] = acc[tj][r4];
                    }
                }
            }
        }
    };

    if (L2RES) {
        int rem = nstrips - blockIdx.x * SS;
        int nit = rem > 0 ? (rem + stride - 1) / stride : 0;
        for (int it = 0; it < nit; ++it) {
            int strip = base + it * stride;
            body(strip, strip < nstrips);
        }
    } else {
        for (int strip = base; strip < nstrips; strip += stride)
            body(strip, true);
    }
}

// ---------------- logits on compact rows: out[i] = yB[i] @ LW + lb ----------------
__global__ void k_logits(const float* __restrict__ x,
                         const float* __restrict__ LW, const float* __restrict__ lb,
                         float* __restrict__ out, int B) {
    int wid = blockIdx.x * 4 + (threadIdx.x >> 6);
    int lane = threadIdx.x & 63;
    if (wid >= B) return;
    if (lane >= 40) return;
    float acc = lb[lane];
    const float4* xr = (const float4*)(x + (size_t)wid * D);
    #pragma unroll 4
    for (int k4 = 0; k4 < 32; k4++) {
        float4 xv = xr[k4];
        acc += xv.x * LW[(4 * k4 + 0) * 40 + lane];
        acc += xv.y * LW[(4 * k4 + 1) * 40 + lane];
        acc += xv.z * LW[(4 * k4 + 2) * 40 + lane];
        acc += xv.w * LW[(4 * k4 + 3) * 40 + lane];
    }
    out[(size_t)wid * 40 + lane] = acc;
}

extern "C" void kernel_launch(void* const* d_in, const int* in_sizes, int n_in,
                              void* d_out, int out_size, void* d_ws, size_t ws_size,
                              hipStream_t stream) {
    const float* node_features = (const float*)d_in[0];
    const int*   edges         = (const int*)d_in[1];
    const float* edge_w        = (const float*)d_in[2];
    const int*   input_idx     = (const int*)d_in[3];
    const int N = in_sizes[0] / D;
    const int E = in_sizes[2];
    const int B = in_sizes[3];

    const float* P[6][6];
    for (int f = 0; f < 6; f++)
        for (int q = 0; q < 6; q++)
            P[f][q] = (const float*)d_in[4 + f * 6 + q];
    const float* logits_w = (const float*)d_in[40];
    const float* logits_b = (const float*)d_in[41];

    float* ws = (float*)d_ws;
    size_t nd = (size_t)N * D;
    float* xA  = ws;
    float* y   = ws + nd;
    float* red = ws + 2 * nd;           // reduce output; reused as compact post-FFN rows
    float* p   = ws + 3 * nd;
    __half* yh = (__half*)p; p += nd / 2;
    const int Ks[6] = {128, 128, 256, 128, 256, 128};
    short* Wh[6]; short* Wl[6]; float* Bp[6];
    {
        short* sp = (short*)p;
        for (int f = 0; f < 6; f++) {
            Wh[f] = sp; sp += (size_t)Ks[f] * D;
            Wl[f] = sp; sp += (size_t)Ks[f] * D;
        }
        p = (float*)sp;
    }
    for (int f = 0; f < 6; f++) { Bp[f] = p; p += D; }
    int* cnt    = (int*)p; p += N;
    float* sums = p; p += 2;                        // adjacent to cnt: single memset
    unsigned* cw = (unsigned*)p; p += (size_t)N * CAP;  // packed buckets (src<<16 | fp16 w)

    // fold args
    FoldArgs fa;
    for (int f = 0; f < 6; f++) {
        fa.g[f] = P[f][0]; fa.be[f] = P[f][1]; fa.mu[f] = P[f][2];
        fa.var[f] = P[f][3]; fa.w[f] = P[f][4]; fa.bi[f] = P[f][5];
        fa.wh[f] = Wh[f]; fa.wl[f] = Wl[f]; fa.bp[f] = Bp[f]; fa.K[f] = Ks[f];
    }

    hipMemsetAsync(cnt, 0, ((size_t)N + 2) * sizeof(int), stream);
    // BN-fold first (fillpre needs FFN0 + FFN1 folded weights)
    k_fold<<<768, 256, 0, stream>>>(fa);
    // fused: edge-bucket fill (256 blocks) + pre-FFN + conv1-prepare (768 blocks)
    k_fillpre<<<1024, 512, 0, stream>>>(edges, edge_w, cnt, sums, cw, E, N,
                                        node_features, Wh[0], Wl[0], Bp[0], xA,
                                        Wh[1], Bp[1], yh);

    const int rb = (N + 3) / 4;
    const int g1 = 256;   // K=256 split3: ~146 KB LDS, 1024 thr -> 16 waves/CU
    const int g2 = 512;   // K=128 split3: ~69 KB LDS -> 2 blocks/CU

    k_reduce<<<rb, 256, 0, stream>>>(cnt, cw, sums, yh, red, N);
    // conv1-update (+l2norm+resid) with FUSED conv2-prepare -> yh
    k_ffn<256, 1024, true,  true,  false, false, true ><<<g1, 1024, 0, stream>>>(
        xA, red, Wh[2], Wl[2], Bp[2], xA, y, nullptr, N, nullptr, Wh[3], Bp[3], yh);
    k_reduce<<<rb, 256, 0, stream>>>(cnt, cw, sums, yh, red, N);
    // conv2-update (+l2norm+resid)
    k_ffn<256, 1024, true,  true,  false, false, false><<<g1, 1024, 0, stream>>>(
        y, red, Wh[4], Wl[4], Bp[4], y, xA, nullptr, N, nullptr, nullptr, nullptr, nullptr);
    // post-FFN on the B gathered rows only (MFMA, compact output into red)
    k_ffn<128, 512,  true,  false, false, true,  false><<<g2, 512, 0, stream>>>(
        xA, nullptr, Wh[5], Wl[5], Bp[5], nullptr, red, nullptr, B, input_idx, nullptr, nullptr, nullptr);
    // logits on compact rows
    k_logits<<<(B + 3) / 4, 256, 0, stream>>>(red, logits_w, logits_b, (float*)d_out, B);
}

// Round 15
// 434.715 us; speedup vs baseline: 1.0080x; 1.0080x over previous
//
#include <hip/hip_runtime.h>
#include <hip/hip_fp16.h>
#include <math.h>

static constexpr int D = 128;
static constexpr int CAP = 64;            // bucket capacity; max degree ~45 for E/N=16 Poisson
static constexpr float EPS_BN = 1e-3f;

typedef short short8 __attribute__((ext_vector_type(8)));
typedef short short4v __attribute__((ext_vector_type(4)));
typedef float float4v __attribute__((ext_vector_type(4)));

__device__ __forceinline__ float gelu_exact(float x) {
    return 0.5f * x * (1.0f + erff(x * 0.70710678118654752f));
}

__device__ __forceinline__ void f32_to_hilo(float f, short& h, short& l) {
    unsigned u = __float_as_uint(f);
    h = (short)(u >> 16);
    float hf = __uint_as_float(u & 0xFFFF0000u);
    unsigned lu = __float_as_uint(f - hf);
    l = (short)(lu >> 16);
}

__device__ __forceinline__ short f32_to_bf16_rne(float f) {
    unsigned u = __float_as_uint(f);
    u += 0x7FFFu + ((u >> 16) & 1u);
    return (short)(u >> 16);
}

__device__ __forceinline__ void cvt_hilo8(const float4& x, const float4& y, short8& h8, short8& l8) {
    short h, l;
    f32_to_hilo(x.x, h, l); h8[0] = h; l8[0] = l;
    f32_to_hilo(x.y, h, l); h8[1] = h; l8[1] = l;
    f32_to_hilo(x.z, h, l); h8[2] = h; l8[2] = l;
    f32_to_hilo(x.w, h, l); h8[3] = h; l8[3] = l;
    f32_to_hilo(y.x, h, l); h8[4] = h; l8[4] = l;
    f32_to_hilo(y.y, h, l); h8[5] = h; l8[5] = l;
    f32_to_hilo(y.z, h, l); h8[6] = h; l8[6] = l;
    f32_to_hilo(y.w, h, l); h8[7] = h; l8[7] = l;
}

__device__ __forceinline__ short8 cvt_rne8(const float4& x, const float4& y) {
    short8 r;
    r[0] = f32_to_bf16_rne(x.x); r[1] = f32_to_bf16_rne(x.y);
    r[2] = f32_to_bf16_rne(x.z); r[3] = f32_to_bf16_rne(x.w);
    r[4] = f32_to_bf16_rne(y.x); r[5] = f32_to_bf16_rne(y.y);
    r[6] = f32_to_bf16_rne(y.z); r[7] = f32_to_bf16_rne(y.w);
    return r;
}

// ---------------- fold args ----------------
struct FoldArgs {
    const float* g[6]; const float* be[6]; const float* mu[6];
    const float* var[6]; const float* w[6]; const float* bi[6];
    short* wh[6]; short* wl[6]; float* bp[6]; int K[6];
};

// ---------------- BN fold (standalone): 6 FFNs' weights -> bf16 hi/lo + folded bias
__global__ void k_fold(FoldArgs fa) {
    __shared__ float sm[4];
    const int tid = threadIdx.x;
    const int lane = tid & 63, wvi = tid >> 6;
    const int f = blockIdx.x >> 7;      // 0..5
    const int c = blockIdx.x & 127;     // 0..127
    const int K = fa.K[f];
    const float* g = fa.g[f]; const float* be = fa.be[f];
    const float* mu = fa.mu[f]; const float* var = fa.var[f];
    const float* w = fa.w[f]; const float* bi = fa.bi[f];
    short* wh = fa.wh[f]; short* wl = fa.wl[f]; float* bp = fa.bp[f];
    float part = 0.f;
    for (int k = tid; k < K; k += blockDim.x) {
        float a = g[k] / sqrtf(var[k] + EPS_BN);
        float wv = w[k * D + c];
        float prod = a * wv;
        short hh, ll;
        f32_to_hilo(prod, hh, ll);
        wh[c * K + k] = hh;
        wl[c * K + k] = ll;
        part += (be[k] - mu[k] * a) * wv;
    }
    for (int off = 32; off > 0; off >>= 1) part += __shfl_down(part, off, 64);
    if (lane == 0) sm[wvi] = part;
    __syncthreads();
    if (tid == 0) bp[c] = bi[c] + sm[0] + sm[1] + sm[2] + sm[3];
}

// ---------------- fused fill + pre-FFN + conv1-prepare ----------------
// R11-proven bit-8 role split (512 fill + 512 pre, co-located per CU). R14's
// 256/768 rebalance was null -> reverted. This round's levers:
//  (a) fill: 4-deep ILP unroll (hoisted dst/src/w loads ahead of the atomic
//      chains -> 4x in-flight atomics; same fix that worked for k_reduce R4->R5)
//  (b) c1p: W1 fragments are loop-invariant across strips -> preload all 16
//      short8 into registers ONCE (removes 16 dependent L2-latency loads per
//      strip from the c1p critical path). launch_bounds(512,4) pins VGPR<=128.
__global__ void __launch_bounds__(512, 4) k_fillpre(
    const int* __restrict__ edges, const float* __restrict__ ew,
    int* __restrict__ cnt, float* __restrict__ sums, unsigned* __restrict__ cw,
    int E, int N,
    const float* __restrict__ A0, const short* __restrict__ Wh,
    const short* __restrict__ Wl, const float* __restrict__ bp,
    float* __restrict__ outf,
    const short* __restrict__ Wh1, const float* __restrict__ bp1,
    __half* __restrict__ yh)
{
    constexpr int K = 128;
    constexpr int WSZ = 128 * K;              // shorts per hi/lo buffer
    __shared__ short Wlds[2 * WSZ];           // 64 KB
    __shared__ short xbuf[2][16][136];        // strip rows as bf16 (pad 136)
    __shared__ float sm[8];

    const int tid = threadIdx.x;
    const int lane = tid & 63;
    const int wvi = tid >> 6;

    const int grp = blockIdx.x >> 8;          // 0..3
    const int role = grp & 1;                 // 0=fill, 1=pre+c1p
    const int rid = ((grp >> 1) << 8) | (blockIdx.x & 255);   // 0..511 within role

    if (role == 0) {
        // ---------------- fill role (512 blocks x 512 thr, 8-group partition) ----
        const int g = rid & 7;
        const int bid = rid >> 3;             // 0..63
        const int gs = 64 * 512;
        const int N8 = (N + 7) >> 3;
        const int lo = g * N8;
        const int hi = min(lo + N8, N);
        float s = 0.f;
        int e = bid * 512 + tid;
        // 4-deep body: hoist loads ahead of the atomic->store chains
        for (; e + 3 * gs < E; e += 4 * gs) {
            int d0 = edges[e];
            int d1 = edges[e + gs];
            int d2 = edges[e + 2 * gs];
            int d3 = edges[e + 3 * gs];
            bool i0 = (d0 >= lo && d0 < hi);
            bool i1 = (d1 >= lo && d1 < hi);
            bool i2 = (d2 >= lo && d2 < hi);
            bool i3 = (d3 >= lo && d3 < hi);
            int s0 = 0, s1 = 0, s2 = 0, s3 = 0;
            float w0 = 0.f, w1 = 0.f, w2 = 0.f, w3 = 0.f;
            if (i0) { s0 = edges[E + e];          w0 = ew[e]; }
            if (i1) { s1 = edges[E + e + gs];     w1 = ew[e + gs]; }
            if (i2) { s2 = edges[E + e + 2 * gs]; w2 = ew[e + 2 * gs]; }
            if (i3) { s3 = edges[E + e + 3 * gs]; w3 = ew[e + 3 * gs]; }
            if (i0) { s += w0; int x = atomicAdd(&cnt[d0], 1);
                if (x < CAP) cw[(size_t)d0 * CAP + x] = ((unsigned)s0 << 16) | (unsigned)__half_as_ushort(__float2half(w0)); }
            if (i1) { s += w1; int x = atomicAdd(&cnt[d1], 1);
                if (x < CAP) cw[(size_t)d1 * CAP + x] = ((unsigned)s1 << 16) | (unsigned)__half_as_ushort(__float2half(w1)); }
            if (i2) { s += w2; int x = atomicAdd(&cnt[d2], 1);
                if (x < CAP) cw[(size_t)d2 * CAP + x] = ((unsigned)s2 << 16) | (unsigned)__half_as_ushort(__float2half(w2)); }
            if (i3) { s += w3; int x = atomicAdd(&cnt[d3], 1);
                if (x < CAP) cw[(size_t)d3 * CAP + x] = ((unsigned)s3 << 16) | (unsigned)__half_as_ushort(__float2half(w3)); }
        }
        for (; e < E; e += gs) {
            int d = edges[e];
            if (d >= lo && d < hi) {
                int src = edges[E + e];
                float w = ew[e];
                s += w;
                int x = atomicAdd(&cnt[d], 1);
                if (x < CAP)
                    cw[(size_t)d * CAP + x] = ((unsigned)src << 16) | (unsigned)__half_as_ushort(__float2half(w));
            }
        }
        for (int off = 32; off > 0; off >>= 1) s += __shfl_down(s, off, 64);
        if (lane == 0) sm[wvi] = s;
        __syncthreads();
        if (tid == 0) {
            float t = 0.f;
            #pragma unroll
            for (int i = 0; i < 8; i++) t += sm[i];
            if (t != 0.f) atomicAdd(sums, t);
        }
        return;
    }

    // ---------------- pre-FFN + c1p role (512 blocks) ----------------
    const int fbid = rid;                     // 0..511
    constexpr int NBLK = 512;

    // stage pre W once: LDS[c*K + k] = W[c*K + (k ^ ((c&7)<<3))]
    #pragma unroll
    for (int it = 0; it < (2 * WSZ) / (512 * 8); ++it) {
        int s = it * 4096 + tid * 8;
        int buf = s / WSZ;
        int rem = s - buf * WSZ;
        int c = rem / K;
        int kk = (rem & (K - 1)) ^ ((c & 7) << 3);
        const short* src = (buf ? Wl : Wh) + c * K + kk;
        *(short8*)&Wlds[s] = *(const short8*)src;
    }
    __syncthreads();

    const int wv = tid >> 6;
    const int ssub = wv >> 2;
    const int wc = wv & 3;
    const int m = lane & 15;
    const int quad = lane >> 4;
    const int nstrips = (N + 15) >> 4;
    constexpr int STRIDE = NBLK * 2;

    // W1 fragments are strip-invariant: preload all 16 short8 into registers
    short8 w1f[2][2][2];
    #pragma unroll
    for (int cc = 0; cc < 2; ++cc)
        #pragma unroll
        for (int ks = 0; ks < 2; ++ks)
            #pragma unroll
            for (int tj = 0; tj < 2; ++tj) {
                const int kk = cc * 64 + ks * 32 + quad * 8;
                const int c = wc * 32 + tj * 16 + m;
                w1f[cc][ks][tj] = *(const short8*)(Wh1 + (size_t)c * 128 + kk);
            }

    // grid-uniform trip count (barriers inside the loop)
    int remw = nstrips - fbid * 2;
    int nit = remw > 0 ? (remw + STRIDE - 1) / STRIDE : 0;

    for (int it = 0; it < nit; ++it) {
        const int strip = fbid * 2 + ssub + it * STRIDE;
        const bool active = strip < nstrips;
        float4v acc[2];
        acc[0] = (float4v){0.f, 0.f, 0.f, 0.f};
        acc[1] = (float4v){0.f, 0.f, 0.f, 0.f};

        if (active) {
            int r = strip * 16 + m;
            if (r >= N) r = N - 1;
            const float* pA0 = A0 + (size_t)r * D;

            float4 a[2][4];
            {
                const float4* s4 = (const float4*)pA0 + quad * 2;
                a[0][0] = s4[0]; a[0][1] = s4[1]; a[0][2] = s4[8]; a[0][3] = s4[9];
            }
            {
                const float4* s4 = (const float4*)(pA0 + 64) + quad * 2;
                a[1][0] = s4[0]; a[1][1] = s4[1]; a[1][2] = s4[8]; a[1][3] = s4[9];
            }

            #pragma unroll
            for (int cc = 0; cc < 2; ++cc) {
                #pragma unroll
                for (int ks = 0; ks < 2; ++ks) {
                    const int kk = cc * 64 + ks * 32 + quad * 8;
                    short8 ah, al;
                    cvt_hilo8(a[cc][ks * 2], a[cc][ks * 2 + 1], ah, al);
                    #pragma unroll
                    for (int tj = 0; tj < 2; ++tj) {
                        const int c = wc * 32 + tj * 16 + m;
                        const int idx = c * K + (kk ^ ((c & 7) << 3));
                        short8 bh = *(const short8*)&Wlds[idx];
                        short8 bl = *(const short8*)&Wlds[WSZ + idx];
                        acc[tj] = __builtin_amdgcn_mfma_f32_16x16x32_bf16(al, bh, acc[tj], 0, 0, 0);
                        acc[tj] = __builtin_amdgcn_mfma_f32_16x16x32_bf16(ah, bl, acc[tj], 0, 0, 0);
                        acc[tj] = __builtin_amdgcn_mfma_f32_16x16x32_bf16(ah, bh, acc[tj], 0, 0, 0);
                    }
                }
            }

            // epilogue: bias + gelu; write xA (f32 global) + xbuf (bf16 LDS)
            #pragma unroll
            for (int tj = 0; tj < 2; ++tj) {
                float bv = bp[wc * 32 + tj * 16 + m];
                #pragma unroll
                for (int r4 = 0; r4 < 4; ++r4)
                    acc[tj][r4] = gelu_exact(acc[tj][r4] + bv);
            }
            #pragma unroll
            for (int r4 = 0; r4 < 4; ++r4) {
                int rib = quad * 4 + r4;
                int row = strip * 16 + rib;
                #pragma unroll
                for (int tj = 0; tj < 2; ++tj) {
                    int col = wc * 32 + tj * 16 + m;
                    if (row < N) outf[(size_t)row * D + col] = acc[tj][r4];
                    xbuf[ssub][rib][col] = f32_to_bf16_rne(acc[tj][r4]);
                }
            }
        }
        __syncthreads();

        if (active) {
            // ---- c1p: yh = gelu(xbuf @ W1 + b1), W1 from REGISTERS ----
            float4v acc2[2];
            acc2[0] = (float4v){0.f, 0.f, 0.f, 0.f};
            acc2[1] = (float4v){0.f, 0.f, 0.f, 0.f};
            #pragma unroll
            for (int cc = 0; cc < 2; ++cc) {
                #pragma unroll
                for (int ks = 0; ks < 2; ++ks) {
                    const int kk = cc * 64 + ks * 32 + quad * 8;
                    short8 ah = *(const short8*)&xbuf[ssub][m][kk];
                    #pragma unroll
                    for (int tj = 0; tj < 2; ++tj)
                        acc2[tj] = __builtin_amdgcn_mfma_f32_16x16x32_bf16(ah, w1f[cc][ks][tj], acc2[tj], 0, 0, 0);
                }
            }
            #pragma unroll
            for (int tj = 0; tj < 2; ++tj) {
                float bv = bp1[wc * 32 + tj * 16 + m];
                #pragma unroll
                for (int r4 = 0; r4 < 4; ++r4)
                    acc2[tj][r4] = gelu_exact(acc2[tj][r4] + bv);
            }
            #pragma unroll
            for (int r4 = 0; r4 < 4; ++r4) {
                int row = strip * 16 + quad * 4 + r4;
                if (row < N) {
                    #pragma unroll
                    for (int tj = 0; tj < 2; ++tj) {
                        int col = wc * 32 + tj * 16 + m;
                        yh[(size_t)row * D + col] = __float2half(acc2[tj][r4]);
                    }
                }
            }
        }
        __syncthreads();                      // xbuf reused next iteration
    }
}

// ---------------- bucket gather-reduce (fp16 payload): red[n] = sum_e w[e]*y[col[e]]
__device__ __forceinline__ void accum8(float* acc, const float4& raw, float w) {
    const __half2* hp = (const __half2*)&raw;
    #pragma unroll
    for (int t = 0; t < 4; t++) {
        float2 f = __half22float2(hp[t]);
        acc[t * 2]     += w * f.x;
        acc[t * 2 + 1] += w * f.y;
    }
}

__global__ void k_reduce(const int* __restrict__ cnt, const unsigned* __restrict__ cw,
                         const float* __restrict__ sums, const __half* __restrict__ y,
                         float* __restrict__ red, int N) {
    int n = blockIdx.x * (blockDim.x >> 6) + (threadIdx.x >> 6);
    if (n >= N) return;
    float inv = 1.0f / sums[0];
    int lane = threadIdx.x & 63;
    int sub = lane >> 4;      // edge slot 0..3
    int q = lane & 15;        // 8-half chunk
    int count = min(cnt[n], CAP);
    int start = n * CAP;
    int end = start + count;
    float acc[8] = {0.f, 0.f, 0.f, 0.f, 0.f, 0.f, 0.f, 0.f};
    int i = start + sub;
    for (; i + 12 < end; i += 16) {
        unsigned c0 = cw[i];
        unsigned c1 = cw[i + 4];
        unsigned c2 = cw[i + 8];
        unsigned c3 = cw[i + 12];
        float4 r0 = *((const float4*)(y + (size_t)(c0 >> 16) * D) + q);
        float4 r1 = *((const float4*)(y + (size_t)(c1 >> 16) * D) + q);
        float4 r2 = *((const float4*)(y + (size_t)(c2 >> 16) * D) + q);
        float4 r3 = *((const float4*)(y + (size_t)(c3 >> 16) * D) + q);
        float w0 = __half2float(__ushort_as_half((unsigned short)(c0 & 0xFFFFu))) * inv;
        float w1 = __half2float(__ushort_as_half((unsigned short)(c1 & 0xFFFFu))) * inv;
        float w2 = __half2float(__ushort_as_half((unsigned short)(c2 & 0xFFFFu))) * inv;
        float w3 = __half2float(__ushort_as_half((unsigned short)(c3 & 0xFFFFu))) * inv;
        accum8(acc, r0, w0);
        accum8(acc, r1, w1);
        accum8(acc, r2, w2);
        accum8(acc, r3, w3);
    }
    for (; i < end; i += 4) {
        unsigned c = cw[i];
        float4 r = *((const float4*)(y + (size_t)(c >> 16) * D) + q);
        float w = __half2float(__ushort_as_half((unsigned short)(c & 0xFFFFu))) * inv;
        accum8(acc, r, w);
    }
    #pragma unroll
    for (int t = 0; t < 8; t++) {
        acc[t] += __shfl_xor(acc[t], 16, 64);
        acc[t] += __shfl_xor(acc[t], 32, 64);
    }
    if (sub == 0) {
        float4 o0 = {acc[0], acc[1], acc[2], acc[3]};
        float4 o1 = {acc[4], acc[5], acc[6], acc[7]};
        *((float4*)(red + (size_t)n * D + q * 8)) = o0;
        *((float4*)(red + (size_t)n * D + q * 8 + 4)) = o1;
    }
}

// ---------------- streaming tall-skinny FFN GEMM, col-split waves ----------------
// BLOCK=1024 for the 128KB-LDS K=256 updates (16 waves/CU; launch_bounds pins
// VGPR cap at 128). FUSEP: fuse the NEXT row-local K=128 FFN (conv2-prepare)
// into the L2RES epilogue via bf16 xbuf exchange (removes a dispatch + 25.6MB
// re-read; ~neutral on time since this kernel is busy — kept for fewer dispatches).
template<int K, int BLOCK, bool SPLIT3, bool L2RES, bool OUT16, bool GATHER, bool FUSEP>
__global__ void __launch_bounds__(BLOCK, BLOCK / 256) k_ffn(
    const float* __restrict__ A0, const float* __restrict__ A1,
    const short* __restrict__ Wh, const short* __restrict__ Wl,
    const float* __restrict__ bp, const float* __restrict__ resid,
    float* __restrict__ outf, __half* __restrict__ outh, int N,
    const int* __restrict__ gidx,
    const short* __restrict__ WhP, const float* __restrict__ bpP,
    __half* __restrict__ yhP)
{
    constexpr int NB = SPLIT3 ? 2 : 1;
    constexpr int WSZ = 128 * K;              // shorts per hi/lo buffer
    constexpr int NC = K / 64;                // 64-wide K chunks
    constexpr int SS = BLOCK / 256;           // strip-subs per block
    __shared__ short Wlds[NB * WSZ];          // 32..128 KB
    __shared__ float rsum[SS][16][4];         // per-strip-sub row partial sums (L2RES)
    __shared__ short xbuf[FUSEP ? SS : 1][16][136];  // FUSEP row exchange

    const int tid = threadIdx.x;

    constexpr int ITER = (NB * WSZ) / (BLOCK * 8);
    #pragma unroll
    for (int it = 0; it < ITER; ++it) {
        int s = it * (BLOCK * 8) + tid * 8;
        int buf = s / WSZ;
        int rem = s - buf * WSZ;
        int c = rem / K;
        int kk = (rem & (K - 1)) ^ ((c & 7) << 3);
        const short* src = (buf ? Wl : Wh) + c * K + kk;
        *(short8*)&Wlds[s] = *(const short8*)src;
    }
    __syncthreads();

    const int lane = tid & 63;
    const int wv = tid >> 6;
    const int ssub = wv >> 2;
    const int wc = wv & 3;
    const int m = lane & 15;
    const int quad = lane >> 4;
    const int nstrips = (N + 15) >> 4;
    const int stride = gridDim.x * SS;
    const int base = blockIdx.x * SS + ssub;

    auto body = [&](int strip, bool active) {
        int rr = active ? strip * 16 + m : m;
        if (rr >= N) rr = N - 1;
        const int r = GATHER ? gidx[rr] : rr;
        const float* pA0 = A0 + (size_t)r * D;
        const float* pA1 = (K == 256) ? (A1 + (size_t)r * D) : pA0;

        float4 a[2][4];
        {
            const float4* s4 = (const float4*)pA0 + quad * 2;
            a[0][0] = s4[0]; a[0][1] = s4[1]; a[0][2] = s4[8]; a[0][3] = s4[9];
        }
        {
            const float4* s4 = (const float4*)(pA0 + 64) + quad * 2;
            a[1][0] = s4[0]; a[1][1] = s4[1]; a[1][2] = s4[8]; a[1][3] = s4[9];
        }

        float4v acc[2];
        acc[0] = (float4v){0.f, 0.f, 0.f, 0.f};
        acc[1] = (float4v){0.f, 0.f, 0.f, 0.f};

        #pragma unroll
        for (int cc = 0; cc < NC; ++cc) {
            #pragma unroll
            for (int ks = 0; ks < 2; ++ks) {
                const int kk = cc * 64 + ks * 32 + quad * 8;
                short8 ah, al;
                if (SPLIT3) cvt_hilo8(a[cc & 1][ks * 2], a[cc & 1][ks * 2 + 1], ah, al);
                else        ah = cvt_rne8(a[cc & 1][ks * 2], a[cc & 1][ks * 2 + 1]);
                #pragma unroll
                for (int tj = 0; tj < 2; ++tj) {
                    const int c = wc * 32 + tj * 16 + m;
                    const int idx = c * K + (kk ^ ((c & 7) << 3));
                    short8 bh = *(const short8*)&Wlds[idx];
                    if (SPLIT3) {
                        short8 bl = *(const short8*)&Wlds[WSZ + idx];
                        acc[tj] = __builtin_amdgcn_mfma_f32_16x16x32_bf16(al, bh, acc[tj], 0, 0, 0);
                        acc[tj] = __builtin_amdgcn_mfma_f32_16x16x32_bf16(ah, bl, acc[tj], 0, 0, 0);
                    }
                    acc[tj] = __builtin_amdgcn_mfma_f32_16x16x32_bf16(ah, bh, acc[tj], 0, 0, 0);
                }
            }
            if (cc + 2 < NC) {
                const int n2 = cc + 2;
                const float* src = (K == 256 && n2 >= 2) ? pA1 : pA0;
                const int kb = (K == 256) ? ((n2 & 1) * 64) : (n2 * 64);
                const float4* s4 = (const float4*)(src + kb) + quad * 2;
                a[cc & 1][0] = s4[0]; a[cc & 1][1] = s4[1];
                a[cc & 1][2] = s4[8]; a[cc & 1][3] = s4[9];
            }
        }

        #pragma unroll
        for (int tj = 0; tj < 2; ++tj) {
            float bv = bp[wc * 32 + tj * 16 + m];
            #pragma unroll
            for (int r4 = 0; r4 < 4; ++r4)
                acc[tj][r4] = gelu_exact(acc[tj][r4] + bv);
        }

        if (L2RES) {
            float ss[4];
            #pragma unroll
            for (int r4 = 0; r4 < 4; ++r4) {
                float v = acc[0][r4] * acc[0][r4] + acc[1][r4] * acc[1][r4];
                v += __shfl_xor(v, 1, 64);
                v += __shfl_xor(v, 2, 64);
                v += __shfl_xor(v, 4, 64);
                v += __shfl_xor(v, 8, 64);
                ss[r4] = v;
            }
            if (m == 0) {
                #pragma unroll
                for (int r4 = 0; r4 < 4; ++r4) rsum[ssub][quad * 4 + r4][wc] = ss[r4];
            }
            __syncthreads();
            #pragma unroll
            for (int r4 = 0; r4 < 4; ++r4) {
                const int rib = quad * 4 + r4;
                float tot = rsum[ssub][rib][0] + rsum[ssub][rib][1]
                          + rsum[ssub][rib][2] + rsum[ssub][rib][3];
                float inv = 1.0f / fmaxf(sqrtf(tot), 1e-12f);
                int row = strip * 16 + rib;
                if (active && row < N) {
                    #pragma unroll
                    for (int tj = 0; tj < 2; ++tj) {
                        int col = wc * 32 + tj * 16 + m;
                        float v = acc[tj][r4] * inv + resid[(size_t)row * D + col];
                        outf[(size_t)row * D + col] = v;
                        if (FUSEP) xbuf[ssub][rib][col] = f32_to_bf16_rne(v);
                    }
                }
            }
            if (FUSEP) {
                __syncthreads();              // xbuf ready
                if (active) {
                    // fused conv2-prepare: yhP = gelu(xbuf @ WP + bP)
                    float4v acc2[2];
                    acc2[0] = (float4v){0.f, 0.f, 0.f, 0.f};
                    acc2[1] = (float4v){0.f, 0.f, 0.f, 0.f};
                    #pragma unroll
                    for (int cc = 0; cc < 2; ++cc) {
                        #pragma unroll
                        for (int ks = 0; ks < 2; ++ks) {
                            const int kk = cc * 64 + ks * 32 + quad * 8;
                            short8 ah = *(const short8*)&xbuf[ssub][m][kk];
                            #pragma unroll
                            for (int tj = 0; tj < 2; ++tj) {
                                const int c = wc * 32 + tj * 16 + m;
                                short8 bh = *(const short8*)(WhP + (size_t)c * 128 + kk);
                                acc2[tj] = __builtin_amdgcn_mfma_f32_16x16x32_bf16(ah, bh, acc2[tj], 0, 0, 0);
                            }
                        }
                    }
                    #pragma unroll
                    for (int tj = 0; tj < 2; ++tj) {
                        float bv = bpP[wc * 32 + tj * 16 + m];
                        #pragma unroll
                        for (int r4 = 0; r4 < 4; ++r4)
                            acc2[tj][r4] = gelu_exact(acc2[tj][r4] + bv);
                    }
                    #pragma unroll
                    for (int r4 = 0; r4 < 4; ++r4) {
                        int row = strip * 16 + quad * 4 + r4;
                        if (row < N) {
                            #pragma unroll
                            for (int tj = 0; tj < 2; ++tj) {
                                int col = wc * 32 + tj * 16 + m;
                                yhP[(size_t)row * D + col] = __float2half(acc2[tj][r4]);
                            }
                        }
                    }
                }
            }
            __syncthreads();                  // rsum/xbuf reused next iteration
        } else {
            #pragma unroll
            for (int r4 = 0; r4 < 4; ++r4) {
                int row = strip * 16 + quad * 4 + r4;
                if (active && row < N) {
                    #pragma unroll
                    for (int tj = 0; tj < 2; ++tj) {
                        int col = wc * 32 + tj * 16 + m;
                        if (OUT16) outh[(size_t)row * D + col] = __float2half(acc[tj][r4]);
                        else       outf[(size_t)row * D + col] = acc[tj][r4];
                    }
                }
            }
        }
    };

    if (L2RES) {
        int rem = nstrips - blockIdx.x * SS;
        int nit = rem > 0 ? (rem + stride - 1) / stride : 0;
        for (int it = 0; it < nit; ++it) {
            int strip = base + it * stride;
            body(strip, strip < nstrips);
        }
    } else {
        for (int strip = base; strip < nstrips; strip += stride)
            body(strip, true);
    }
}

// ---------------- logits on compact rows: out[i] = yB[i] @ LW + lb ----------------
__global__ void k_logits(const float* __restrict__ x,
                         const float* __restrict__ LW, const float* __restrict__ lb,
                         float* __restrict__ out, int B) {
    int wid = blockIdx.x * 4 + (threadIdx.x >> 6);
    int lane = threadIdx.x & 63;
    if (wid >= B) return;
    if (lane >= 40) return;
    float acc = lb[lane];
    const float4* xr = (const float4*)(x + (size_t)wid * D);
    #pragma unroll 4
    for (int k4 = 0; k4 < 32; k4++) {
        float4 xv = xr[k4];
        acc += xv.x * LW[(4 * k4 + 0) * 40 + lane];
        acc += xv.y * LW[(4 * k4 + 1) * 40 + lane];
        acc += xv.z * LW[(4 * k4 + 2) * 40 + lane];
        acc += xv.w * LW[(4 * k4 + 3) * 40 + lane];
    }
    out[(size_t)wid * 40 + lane] = acc;
}

extern "C" void kernel_launch(void* const* d_in, const int* in_sizes, int n_in,
                              void* d_out, int out_size, void* d_ws, size_t ws_size,
                              hipStream_t stream) {
    const float* node_features = (const float*)d_in[0];
    const int*   edges         = (const int*)d_in[1];
    const float* edge_w        = (const float*)d_in[2];
    const int*   input_idx     = (const int*)d_in[3];
    const int N = in_sizes[0] / D;
    const int E = in_sizes[2];
    const int B = in_sizes[3];

    const float* P[6][6];
    for (int f = 0; f < 6; f++)
        for (int q = 0; q < 6; q++)
            P[f][q] = (const float*)d_in[4 + f * 6 + q];
    const float* logits_w = (const float*)d_in[40];
    const float* logits_b = (const float*)d_in[41];

    float* ws = (float*)d_ws;
    size_t nd = (size_t)N * D;
    float* xA  = ws;
    float* y   = ws + nd;
    float* red = ws + 2 * nd;           // reduce output; reused as compact post-FFN rows
    float* p   = ws + 3 * nd;
    __half* yh = (__half*)p; p += nd / 2;
    const int Ks[6] = {128, 128, 256, 128, 256, 128};
    short* Wh[6]; short* Wl[6]; float* Bp[6];
    {
        short* sp = (short*)p;
        for (int f = 0; f < 6; f++) {
            Wh[f] = sp; sp += (size_t)Ks[f] * D;
            Wl[f] = sp; sp += (size_t)Ks[f] * D;
        }
        p = (float*)sp;
    }
    for (int f = 0; f < 6; f++) { Bp[f] = p; p += D; }
    int* cnt    = (int*)p; p += N;
    float* sums = p; p += 2;                        // adjacent to cnt: single memset
    unsigned* cw = (unsigned*)p; p += (size_t)N * CAP;  // packed buckets (src<<16 | fp16 w)

    // fold args
    FoldArgs fa;
    for (int f = 0; f < 6; f++) {
        fa.g[f] = P[f][0]; fa.be[f] = P[f][1]; fa.mu[f] = P[f][2];
        fa.var[f] = P[f][3]; fa.w[f] = P[f][4]; fa.bi[f] = P[f][5];
        fa.wh[f] = Wh[f]; fa.wl[f] = Wl[f]; fa.bp[f] = Bp[f]; fa.K[f] = Ks[f];
    }

    hipMemsetAsync(cnt, 0, ((size_t)N + 2) * sizeof(int), stream);
    // BN-fold first (fillpre needs FFN0 + FFN1 folded weights)
    k_fold<<<768, 256, 0, stream>>>(fa);
    // fused: edge-bucket fill (512) + pre-FFN + conv1-prepare (512), bit-8 co-location
    k_fillpre<<<1024, 512, 0, stream>>>(edges, edge_w, cnt, sums, cw, E, N,
                                        node_features, Wh[0], Wl[0], Bp[0], xA,
                                        Wh[1], Bp[1], yh);

    const int rb = (N + 3) / 4;
    const int g1 = 256;   // K=256 split3: ~146 KB LDS, 1024 thr -> 16 waves/CU
    const int g2 = 512;   // K=128 split3: ~69 KB LDS -> 2 blocks/CU

    k_reduce<<<rb, 256, 0, stream>>>(cnt, cw, sums, yh, red, N);
    // conv1-update (+l2norm+resid) with FUSED conv2-prepare -> yh
    k_ffn<256, 1024, true,  true,  false, false, true ><<<g1, 1024, 0, stream>>>(
        xA, red, Wh[2], Wl[2], Bp[2], xA, y, nullptr, N, nullptr, Wh[3], Bp[3], yh);
    k_reduce<<<rb, 256, 0, stream>>>(cnt, cw, sums, yh, red, N);
    // conv2-update (+l2norm+resid)
    k_ffn<256, 1024, true,  true,  false, false, false><<<g1, 1024, 0, stream>>>(
        y, red, Wh[4], Wl[4], Bp[4], y, xA, nullptr, N, nullptr, nullptr, nullptr, nullptr);
    // post-FFN on the B gathered rows only (MFMA, compact output into red)
    k_ffn<128, 512,  true,  false, false, true,  false><<<g2, 512, 0, stream>>>(
        xA, nullptr, Wh[5], Wl[5], Bp[5], nullptr, red, nullptr, B, input_idx, nullptr, nullptr, nullptr);
    // logits on compact rows
    k_logits<<<(B + 3) / 4, 256, 0, stream>>>(red, logits_w, logits_b, (float*)d_out, B);
}